// Round 4
// baseline (162.906 us; speedup 1.0000x reference)
//
#include <hip/hip_runtime.h>
#include <hip/hip_bf16.h>

// GraphResBlock: B=8, N=256, F=64(N_IN), H=128(N_HID), E=16(EIN)
// pair[b,i,j,h] = e[b,i,j,:]@We[:,h] + x[b,j,:]@Wf[:,h] + (x[b,i,:]@Wt[:,h] + bf+bt+be)
// out[b,i,:] = relu(mean_j!=i relu(pair)) @ W1 + b1) @ W2 + b2 + x[b,i]
// K-extended MFMA: A' = [e(16) | x(64)]  (K=80, 5 chunks of 16), B' = [We ; Wf] prepacked bf16.
// net' folded into MFMA C-init (column-constant).

#define BB 8
#define NN 256
#define FF 64
#define HH 128
#define EE 16
#define NCH 5   // K chunks: 0 = We(16), 1..4 = Wf(64)

typedef __attribute__((ext_vector_type(8))) short bf16x8;
typedef __attribute__((ext_vector_type(16))) float f32x16;

__device__ __forceinline__ short f2bf(float f) {
    union { float f; unsigned u; } v; v.f = f;
    unsigned r = v.u + 0x7FFFu + ((v.u >> 16) & 1u);   // RNE
    return (short)(r >> 16);
}
__device__ __forceinline__ float bf2f(short s) {
    union { unsigned u; float f; } v; v.u = ((unsigned)(unsigned short)s) << 16;
    return v.f;
}

// ---------------- Kernel P: pack B' = [We;Wf] into MFMA fragment layout ----------------
// Bpack[ch][ht][lane][el] (bf16): k_local = 8*(lane>>5)+el, h = ht*32+(lane&31)
__global__ __launch_bounds__(256) void k_pack(
    const float* __restrict__ We, const float* __restrict__ Wf,
    short* __restrict__ Bpack)
{
    const int total = NCH * 4 * 64 * 8;   // 10240
    for (int t = blockIdx.x * 256 + threadIdx.x; t < total; t += gridDim.x * 256) {
        const int el   = t & 7;
        const int lane = (t >> 3) & 63;
        const int ht   = (t >> 9) & 3;
        const int ch   = t >> 11;
        const int kl   = 8 * (lane >> 5) + el;
        const int h    = ht * 32 + (lane & 31);
        const float v  = (ch == 0) ? We[kl * HH + h] : Wf[(16 * (ch - 1) + kl) * HH + h];
        Bpack[t] = f2bf(v);
    }
}

// ---------------- Kernel 1: net' = x@Wt + (bf+bt+be)  and  xbf = bf16(x) ----------------
__global__ __launch_bounds__(128) void k_prep(
    const float* __restrict__ x,
    const float* __restrict__ Wt,
    const float* __restrict__ bf, const float* __restrict__ bt, const float* __restrict__ be,
    float* __restrict__ net, short* __restrict__ xbf)
{
    __shared__ float smx[4 * FF];
    const int tid = threadIdx.x;
    const int row0 = blockIdx.x * 4;

    smx[tid]       = x[(size_t)row0 * FF + tid];
    smx[tid + 128] = x[(size_t)row0 * FF + tid + 128];
    __syncthreads();

    const int h = tid;
    const float bsum = bf[h] + bt[h] + be[h];
    float a0 = bsum, a1 = bsum, a2 = bsum, a3 = bsum;

    #pragma unroll 8
    for (int k = 0; k < FF; ++k) {
        const float wt = Wt[k * HH + h];
        a0 = fmaf(smx[k], wt, a0);
        a1 = fmaf(smx[FF + k], wt, a1);
        a2 = fmaf(smx[2 * FF + k], wt, a2);
        a3 = fmaf(smx[3 * FF + k], wt, a3);
    }
    net[(size_t)(row0 + 0) * HH + h] = a0;
    net[(size_t)(row0 + 1) * HH + h] = a1;
    net[(size_t)(row0 + 2) * HH + h] = a2;
    net[(size_t)(row0 + 3) * HH + h] = a3;

    // bf16 copy of x: 4 rows * 64 = 256 values, 2 per thread
    const int r = tid >> 6, f = tid & 63;
    xbf[(size_t)(row0 + r) * FF + f]     = f2bf(smx[r * FF + f]);
    xbf[(size_t)(row0 + r + 2) * FF + f] = f2bf(smx[(r + 2) * FF + f]);
}

// ---------------- Kernel 2: K-extended MFMA pair + relu + mean + MLP + residual ----------------
// One block per (b,i), 256 threads = 4 waves; each wave: 2 j-tiles x 4 h-tiles, K=80.
__global__ __launch_bounds__(256) void k_pair_mfma(
    const float* __restrict__ x, const float* __restrict__ e,
    const float* __restrict__ We, const float* __restrict__ Wf,
    const float* __restrict__ net, const short* __restrict__ xbf,
    const short* __restrict__ Bpack,
    const float* __restrict__ W1, const float* __restrict__ b1,
    const float* __restrict__ W2, const float* __restrict__ b2,
    float* __restrict__ out)
{
    const int row  = blockIdx.x;            // b*256 + i
    const int b    = row >> 8;
    const int i    = row & (NN - 1);
    const int tid  = threadIdx.x;
    const int wave = tid >> 6;
    const int lane = tid & 63;
    const int c    = lane & 31;
    const int half = lane >> 5;

    __shared__ float smred[4][HH];
    __shared__ float sm_ne[HH];
    __shared__ float sm_h1[HH];

    // ---- B' fragments: one coalesced dwordx4 each, already in fragment layout ----
    const bf16x8* __restrict__ bp = (const bf16x8*)Bpack;
    bf16x8 bfrag[NCH][4];
    #pragma unroll
    for (int ch = 0; ch < NCH; ++ch)
        #pragma unroll
        for (int ht = 0; ht < 4; ++ht)
            bfrag[ch][ht] = bp[(ch * 4 + ht) * 64 + lane];

    float netv[4];
    #pragma unroll
    for (int ht = 0; ht < 4; ++ht) netv[ht] = net[(size_t)row * HH + ht * 32 + c];

    const float* __restrict__ eRow = e + (size_t)row * (NN * EE);
    const short* __restrict__ xb   = xbf + (size_t)b * (NN * FF);

    float acc[4] = {0.f, 0.f, 0.f, 0.f};

    #pragma unroll
    for (int q = 0; q < 2; ++q) {
        const int jt = wave * 2 + q;
        const int j  = jt * 32 + c;

        // A chunk 0: e[b,i,j, 8*half .. +8] -> bf16
        const float4* ap = (const float4*)(eRow + (size_t)j * EE + 8 * half);
        const float4 p0 = ap[0];
        const float4 p1 = ap[1];
        bf16x8 ae;
        ae[0] = f2bf(p0.x); ae[1] = f2bf(p0.y); ae[2] = f2bf(p0.z); ae[3] = f2bf(p0.w);
        ae[4] = f2bf(p1.x); ae[5] = f2bf(p1.y); ae[6] = f2bf(p1.z); ae[7] = f2bf(p1.w);

        // A chunks 1..4: xbf[b,j, 16*(ch-1)+8*half .. +8] (pre-converted bf16)
        const bf16x8* xp = (const bf16x8*)(xb + (size_t)j * FF + 8 * half);
        bf16x8 ax0 = xp[0];   // f = 8*half + 0..7      (chunk 1)
        bf16x8 ax1 = xp[2];   // f = 16 + 8*half + ...  (chunk 2)
        bf16x8 ax2 = xp[4];   // chunk 3
        bf16x8 ax3 = xp[6];   // chunk 4

        #pragma unroll
        for (int ht = 0; ht < 4; ++ht) {
            // C-init with net' (all regs of a column share h = ht*32+c)
            const float nv = netv[ht];
            f32x16 d = {nv,nv,nv,nv, nv,nv,nv,nv, nv,nv,nv,nv, nv,nv,nv,nv};
            d = __builtin_amdgcn_mfma_f32_32x32x16_bf16(ae,  bfrag[0][ht], d, 0, 0, 0);
            d = __builtin_amdgcn_mfma_f32_32x32x16_bf16(ax0, bfrag[1][ht], d, 0, 0, 0);
            d = __builtin_amdgcn_mfma_f32_32x32x16_bf16(ax1, bfrag[2][ht], d, 0, 0, 0);
            d = __builtin_amdgcn_mfma_f32_32x32x16_bf16(ax2, bfrag[3][ht], d, 0, 0, 0);
            d = __builtin_amdgcn_mfma_f32_32x32x16_bf16(ax3, bfrag[4][ht], d, 0, 0, 0);
            #pragma unroll
            for (int r = 0; r < 16; ++r) acc[ht] += fmaxf(d[r], 0.f);
        }
    }

    // combine the two lane-halves (disjoint j-rows, same h column)
    #pragma unroll
    for (int ht = 0; ht < 4; ++ht) acc[ht] += __shfl_xor(acc[ht], 32);
    if (lane < 32) {
        #pragma unroll
        for (int ht = 0; ht < 4; ++ht) smred[wave][ht * 32 + c] = acc[ht];
    }
    __syncthreads();

    // ---- combine waves, subtract bf16-matched diagonal, mean ----
    if (tid < HH) {
        const int h = tid;
        float s = smred[0][h] + smred[1][h] + smred[2][h] + smred[3][h];
        float dd = net[(size_t)row * HH + h];
        const float* ed = eRow + (size_t)i * EE;
        #pragma unroll
        for (int k = 0; k < EE; ++k)
            dd = fmaf(bf2f(f2bf(ed[k])), bf2f(f2bf(We[k * HH + h])), dd);
        const short* xd = xb + (size_t)i * FF;
        #pragma unroll 8
        for (int f = 0; f < FF; ++f)
            dd = fmaf(bf2f(xd[f]), bf2f(f2bf(Wf[f * HH + h])), dd);
        s -= fmaxf(dd, 0.f);
        sm_ne[h] = s * (1.0f / (float)NN);
    }
    __syncthreads();

    // ---- h1 = relu(node_emb @ W1 + b1) ----
    if (tid < HH) {
        const int h = tid;
        float a1 = b1[h];
        #pragma unroll 4
        for (int k = 0; k < HH; ++k) a1 = fmaf(sm_ne[k], W1[k * HH + h], a1);
        sm_h1[h] = fmaxf(a1, 0.f);
    }
    __syncthreads();

    // ---- out = h1 @ W2 + b2 + x ----
    if (tid < FF) {
        const int h = tid;
        float a2 = b2[h] + x[(size_t)row * FF + h];
        #pragma unroll 4
        for (int k = 0; k < HH; ++k) a2 = fmaf(sm_h1[k], W2[k * FF + h], a2);
        out[(size_t)row * FF + h] = a2;
    }
}

extern "C" void kernel_launch(void* const* d_in, const int* in_sizes, int n_in,
                              void* d_out, int out_size, void* d_ws, size_t ws_size,
                              hipStream_t stream) {
    (void)in_sizes; (void)n_in; (void)out_size; (void)ws_size;
    const float* x  = (const float*)d_in[0];
    const float* e  = (const float*)d_in[1];
    const float* Wf = (const float*)d_in[2];
    const float* bf = (const float*)d_in[3];
    const float* Wt = (const float*)d_in[4];
    const float* bt = (const float*)d_in[5];
    const float* We = (const float*)d_in[6];
    const float* be = (const float*)d_in[7];
    const float* W1 = (const float*)d_in[8];
    const float* b1 = (const float*)d_in[9];
    const float* W2 = (const float*)d_in[10];
    const float* b2 = (const float*)d_in[11];
    float* out = (float*)d_out;

    // workspace: net [2048][128] f32 (1 MB) | xbf [2048][64] bf16 (256 KB) | Bpack (20 KB)
    float* net   = (float*)d_ws;
    short* xbf   = (short*)((char*)d_ws + (size_t)BB * NN * HH * 4);
    short* Bpack = (short*)((char*)d_ws + (size_t)BB * NN * HH * 4 + (size_t)BB * NN * FF * 2);

    k_pack<<<16, 256, 0, stream>>>(We, Wf, Bpack);
    k_prep<<<(BB * NN) / 4, 128, 0, stream>>>(x, Wt, bf, bt, be, net, xbf);
    k_pair_mfma<<<BB * NN, 256, 0, stream>>>(x, e, We, Wf, net, xbf, Bpack,
                                             W1, b1, W2, b2, out);
}

// Round 5
// 160.488 us; speedup vs baseline: 1.0151x; 1.0151x over previous
//
#include <hip/hip_runtime.h>
#include <hip/hip_bf16.h>

// GraphResBlock: B=8, N=256, F=64(N_IN), H=128(N_HID), E=16(EIN)
// pair[b,i,j,h] = e[b,i,j,:]@We[:,h] + x[b,j,:]@Wf[:,h] + (x[b,i,:]@Wt[:,h] + bf+bt+be)
// out[b,i,:] = relu(mean_{j!=i} relu(pair)) @ W1 + b1) @ W2 + b2 + x[b,i]
// K-extended MFMA: A' = [e(16) | x(64)] (K=80 = 5 chunks of 16), B' = [We;Wf] prepacked bf16.
// net' folded into MFMA C-init. Wave w owns h-tile w (bfrag[5] = 20 VGPR only) and all 8 j-tiles.

#define BB 8
#define NN 256
#define FF 64
#define HH 128
#define EE 16
#define NCH 5   // K chunks: 0 = We(16), 1..4 = Wf(64)

typedef __attribute__((ext_vector_type(8))) short bf16x8;
typedef __attribute__((ext_vector_type(16))) float f32x16;

__device__ __forceinline__ short f2bf(float f) {
    union { float f; unsigned u; } v; v.f = f;
    unsigned r = v.u + 0x7FFFu + ((v.u >> 16) & 1u);   // RNE
    return (short)(r >> 16);
}
__device__ __forceinline__ float bf2f(short s) {
    union { unsigned u; float f; } v; v.u = ((unsigned)(unsigned short)s) << 16;
    return v.f;
}

// ---------------- Kernel 1: net' = x@Wt + (bf+bt+be); xbf = bf16(x); Bpack (blocks<16) ----------------
__global__ __launch_bounds__(128) void k_prep(
    const float* __restrict__ x,
    const float* __restrict__ Wt,
    const float* __restrict__ bf, const float* __restrict__ bt, const float* __restrict__ be,
    const float* __restrict__ We, const float* __restrict__ Wf,
    float* __restrict__ net, short* __restrict__ xbf, short* __restrict__ Bpack)
{
    __shared__ float smx[4 * FF];
    const int tid = threadIdx.x;
    const int row0 = blockIdx.x * 4;

    smx[tid]       = x[(size_t)row0 * FF + tid];
    smx[tid + 128] = x[(size_t)row0 * FF + tid + 128];
    __syncthreads();

    const int h = tid;
    const float bsum = bf[h] + bt[h] + be[h];
    float a0 = bsum, a1 = bsum, a2 = bsum, a3 = bsum;

    #pragma unroll 8
    for (int k = 0; k < FF; ++k) {
        const float wt = Wt[k * HH + h];
        a0 = fmaf(smx[k], wt, a0);
        a1 = fmaf(smx[FF + k], wt, a1);
        a2 = fmaf(smx[2 * FF + k], wt, a2);
        a3 = fmaf(smx[3 * FF + k], wt, a3);
    }
    net[(size_t)(row0 + 0) * HH + h] = a0;
    net[(size_t)(row0 + 1) * HH + h] = a1;
    net[(size_t)(row0 + 2) * HH + h] = a2;
    net[(size_t)(row0 + 3) * HH + h] = a3;

    // bf16 copy of x: 4 rows * 64 = 256 values, 2 per thread
    const int r = tid >> 6, f = tid & 63;
    xbf[(size_t)(row0 + r) * FF + f]     = f2bf(smx[r * FF + f]);
    xbf[(size_t)(row0 + r + 2) * FF + f] = f2bf(smx[(r + 2) * FF + f]);

    // pack B' = [We;Wf] into MFMA fragment layout: Bpack[ch][ht][lane][el],
    // k_local = 8*(lane>>5)+el, h = ht*32+(lane&31)
    if (blockIdx.x < 16) {
        for (int t = blockIdx.x * 128 + tid; t < NCH * 4 * 64 * 8; t += 16 * 128) {
            const int el   = t & 7;
            const int lane = (t >> 3) & 63;
            const int ht   = (t >> 9) & 3;
            const int ch   = t >> 11;
            const int kl   = 8 * (lane >> 5) + el;
            const int hh   = ht * 32 + (lane & 31);
            const float v  = (ch == 0) ? We[kl * HH + hh] : Wf[(16 * (ch - 1) + kl) * HH + hh];
            Bpack[t] = f2bf(v);
        }
    }
}

// ---------------- Kernel 2: K-extended MFMA pair + relu + mean + MLP + residual ----------------
// One block per (b,i), 256 threads = 4 waves. Wave w: h-tile w, all 8 j-tiles, K=80.
__global__ __launch_bounds__(256) void k_pair_mfma(
    const float* __restrict__ x, const float* __restrict__ e,
    const float* __restrict__ We, const float* __restrict__ Wf,
    const float* __restrict__ net, const short* __restrict__ xbf,
    const short* __restrict__ Bpack,
    const float* __restrict__ W1, const float* __restrict__ b1,
    const float* __restrict__ W2, const float* __restrict__ b2,
    float* __restrict__ out)
{
    const int row  = blockIdx.x;            // b*256 + i
    const int b    = row >> 8;
    const int i    = row & (NN - 1);
    const int tid  = threadIdx.x;
    const int wave = tid >> 6;              // = my h-tile
    const int lane = tid & 63;
    const int c    = lane & 31;
    const int half = lane >> 5;

    __shared__ float sm_raw[HH];
    __shared__ float sm_ne[HH];
    __shared__ float sm_h1[HH];

    // ---- B' fragments for MY h-tile only: 5 coalesced 16B loads (L2-broadcast) ----
    const bf16x8* __restrict__ bp = (const bf16x8*)Bpack;
    bf16x8 bfrag[NCH];
    #pragma unroll
    for (int ch = 0; ch < NCH; ++ch)
        bfrag[ch] = bp[(ch * 4 + wave) * 64 + lane];

    const float netv = net[(size_t)row * HH + wave * 32 + c];

    const float* __restrict__ eRow = e + (size_t)row * (NN * EE);
    const short* __restrict__ xb   = xbf + (size_t)b * (NN * FF);

    float acc = 0.f;

    #pragma unroll 2
    for (int jt = 0; jt < 8; ++jt) {
        const int j = jt * 32 + c;

        // A chunk 0: e[b,i,j, 8*half .. +8] -> bf16
        const float4* ap = (const float4*)(eRow + (size_t)j * EE + 8 * half);
        const float4 p0 = ap[0];
        const float4 p1 = ap[1];
        bf16x8 ae;
        ae[0] = f2bf(p0.x); ae[1] = f2bf(p0.y); ae[2] = f2bf(p0.z); ae[3] = f2bf(p0.w);
        ae[4] = f2bf(p1.x); ae[5] = f2bf(p1.y); ae[6] = f2bf(p1.z); ae[7] = f2bf(p1.w);

        // A chunks 1..4: xbf[b,j, 16*(ch-1)+8*half .. +8]
        const bf16x8* xp = (const bf16x8*)(xb + (size_t)j * FF + 8 * half);
        const bf16x8 ax0 = xp[0];
        const bf16x8 ax1 = xp[2];
        const bf16x8 ax2 = xp[4];
        const bf16x8 ax3 = xp[6];

        const float nv = netv;
        f32x16 d = {nv,nv,nv,nv, nv,nv,nv,nv, nv,nv,nv,nv, nv,nv,nv,nv};
        d = __builtin_amdgcn_mfma_f32_32x32x16_bf16(ae,  bfrag[0], d, 0, 0, 0);
        d = __builtin_amdgcn_mfma_f32_32x32x16_bf16(ax0, bfrag[1], d, 0, 0, 0);
        d = __builtin_amdgcn_mfma_f32_32x32x16_bf16(ax1, bfrag[2], d, 0, 0, 0);
        d = __builtin_amdgcn_mfma_f32_32x32x16_bf16(ax2, bfrag[3], d, 0, 0, 0);
        d = __builtin_amdgcn_mfma_f32_32x32x16_bf16(ax3, bfrag[4], d, 0, 0, 0);
        #pragma unroll
        for (int r = 0; r < 16; ++r) acc += fmaxf(d[r], 0.f);
    }

    // combine the two lane-halves (disjoint j-rows, same h)
    acc += __shfl_xor(acc, 32);
    if (lane < 32) sm_raw[wave * 32 + c] = acc;
    __syncthreads();

    // ---- subtract bf16-matched diagonal, mean ----
    if (tid < HH) {
        const int h = tid;
        float dd = net[(size_t)row * HH + h];
        const float* ed = eRow + (size_t)i * EE;
        #pragma unroll
        for (int k = 0; k < EE; ++k)
            dd = fmaf(bf2f(f2bf(ed[k])), bf2f(f2bf(We[k * HH + h])), dd);
        const short* xd = xb + (size_t)i * FF;
        #pragma unroll 8
        for (int f = 0; f < FF; ++f)
            dd = fmaf(bf2f(xd[f]), bf2f(f2bf(Wf[f * HH + h])), dd);
        sm_ne[h] = (sm_raw[h] - fmaxf(dd, 0.f)) * (1.0f / (float)NN);
    }
    __syncthreads();

    // ---- h1 = relu(node_emb @ W1 + b1) ----
    if (tid < HH) {
        const int h = tid;
        float a1 = b1[h];
        #pragma unroll 4
        for (int k = 0; k < HH; ++k) a1 = fmaf(sm_ne[k], W1[k * HH + h], a1);
        sm_h1[h] = fmaxf(a1, 0.f);
    }
    __syncthreads();

    // ---- out = h1 @ W2 + b2 + x ----
    if (tid < FF) {
        const int h = tid;
        float a2 = b2[h] + x[(size_t)row * FF + h];
        #pragma unroll 4
        for (int k = 0; k < HH; ++k) a2 = fmaf(sm_h1[k], W2[k * FF + h], a2);
        out[(size_t)row * FF + h] = a2;
    }
}

extern "C" void kernel_launch(void* const* d_in, const int* in_sizes, int n_in,
                              void* d_out, int out_size, void* d_ws, size_t ws_size,
                              hipStream_t stream) {
    (void)in_sizes; (void)n_in; (void)out_size; (void)ws_size;
    const float* x  = (const float*)d_in[0];
    const float* e  = (const float*)d_in[1];
    const float* Wf = (const float*)d_in[2];
    const float* bf = (const float*)d_in[3];
    const float* Wt = (const float*)d_in[4];
    const float* bt = (const float*)d_in[5];
    const float* We = (const float*)d_in[6];
    const float* be = (const float*)d_in[7];
    const float* W1 = (const float*)d_in[8];
    const float* b1 = (const float*)d_in[9];
    const float* W2 = (const float*)d_in[10];
    const float* b2 = (const float*)d_in[11];
    float* out = (float*)d_out;

    // workspace: net [2048][128] f32 (1 MB) | xbf [2048][64] bf16 (256 KB) | Bpack (20 KB)
    float* net   = (float*)d_ws;
    short* xbf   = (short*)((char*)d_ws + (size_t)BB * NN * HH * 4);
    short* Bpack = (short*)((char*)d_ws + (size_t)BB * NN * HH * 4 + (size_t)BB * NN * FF * 2);

    k_prep<<<(BB * NN) / 4, 128, 0, stream>>>(x, Wt, bf, bt, be, We, Wf, net, xbf, Bpack);
    k_pair_mfma<<<BB * NN, 256, 0, stream>>>(x, e, We, Wf, net, xbf, Bpack,
                                             W1, b1, W2, b2, out);
}

// Round 6
// 138.478 us; speedup vs baseline: 1.1764x; 1.1589x over previous
//
#include <hip/hip_runtime.h>
#include <hip/hip_bf16.h>

// GraphResBlock: B=8, N=256, F=64(N_IN), H=128(N_HID), E=16(EIN)
// pair[b,i,j,h] = e[b,i,j,:]@We[:,h] + x[b,j,:]@Wf[:,h] + net'[b,i,h]
//   (net' = x@Wt + bf+bt+be)
// S[b,i,h] = sum_j relu(pair)   (incl. j=i)   -> k_pair (MFMA, K=80)
// ne = (S - relu(diag))/256 ; out = relu(ne@W1+b1)@W2+b2+x  -> k_mlp (MFMA)

#define BB 8
#define NN 256
#define FF 64
#define HH 128
#define EE 16
#define NCH 5   // K chunks for pair: 0 = We(16), 1..4 = Wf(64)

typedef __attribute__((ext_vector_type(8))) short bf16x8;
typedef __attribute__((ext_vector_type(16))) float f32x16;

__device__ __forceinline__ short f2bf(float f) {
    union { float f; unsigned u; } v; v.f = f;
    unsigned r = v.u + 0x7FFFu + ((v.u >> 16) & 1u);   // RNE
    return (short)(r >> 16);
}
__device__ __forceinline__ float bf2f(short s) {
    union { unsigned u; float f; } v; v.u = ((unsigned)(unsigned short)s) << 16;
    return v.f;
}
// packed RNE conversion: dst = {bf16(lo), bf16(hi)}
__device__ __forceinline__ unsigned pkbf(float lo, float hi) {
    unsigned r;
    asm("v_cvt_pk_bf16_f32 %0, %1, %2" : "=v"(r) : "v"(lo), "v"(hi));
    return r;
}
union bfu { bf16x8 v; unsigned u[4]; };

// ---------------- Kernel 1: net' = x@Wt + (bf+bt+be); xbf = bf16(x); pack B'/W1/W2 ----------------
__global__ __launch_bounds__(128) void k_prep(
    const float* __restrict__ x, const float* __restrict__ Wt,
    const float* __restrict__ bf, const float* __restrict__ bt, const float* __restrict__ be,
    const float* __restrict__ We, const float* __restrict__ Wf,
    const float* __restrict__ W1, const float* __restrict__ W2,
    float* __restrict__ net, short* __restrict__ xbf,
    short* __restrict__ Bpack, short* __restrict__ W1p, short* __restrict__ W2p)
{
    __shared__ float smx[4 * FF];
    const int tid = threadIdx.x;
    const int row0 = blockIdx.x * 4;

    smx[tid]       = x[(size_t)row0 * FF + tid];
    smx[tid + 128] = x[(size_t)row0 * FF + tid + 128];
    __syncthreads();

    const int h = tid;
    const float bsum = bf[h] + bt[h] + be[h];
    float a0 = bsum, a1 = bsum, a2 = bsum, a3 = bsum;

    #pragma unroll 8
    for (int k = 0; k < FF; ++k) {
        const float wt = Wt[k * HH + h];
        a0 = fmaf(smx[k], wt, a0);
        a1 = fmaf(smx[FF + k], wt, a1);
        a2 = fmaf(smx[2 * FF + k], wt, a2);
        a3 = fmaf(smx[3 * FF + k], wt, a3);
    }
    net[(size_t)(row0 + 0) * HH + h] = a0;
    net[(size_t)(row0 + 1) * HH + h] = a1;
    net[(size_t)(row0 + 2) * HH + h] = a2;
    net[(size_t)(row0 + 3) * HH + h] = a3;

    const int r = tid >> 6, f = tid & 63;
    xbf[(size_t)(row0 + r) * FF + f]     = f2bf(smx[r * FF + f]);
    xbf[(size_t)(row0 + r + 2) * FF + f] = f2bf(smx[(r + 2) * FF + f]);

    // ---- pack B'=[We;Wf] (10240), W1 (16384), W2 (8192) into MFMA frag layout ----
    // layout [ch][ht][lane][el]: k = 16*ch_local + 8*(lane>>5) + el, h = ht*32 + (lane&31)
    if (blockIdx.x < 32) {
        for (int t = blockIdx.x * 128 + tid; t < 34816; t += 32 * 128) {
            if (t < 10240) {
                const int el = t & 7, lane = (t >> 3) & 63, ht = (t >> 9) & 3, ch = t >> 11;
                const int kl = 8 * (lane >> 5) + el;
                const int hh = ht * 32 + (lane & 31);
                Bpack[t] = f2bf(ch == 0 ? We[kl * HH + hh] : Wf[(16 * (ch - 1) + kl) * HH + hh]);
            } else if (t < 26624) {
                const int t2 = t - 10240;
                const int el = t2 & 7, lane = (t2 >> 3) & 63, ht = (t2 >> 9) & 3, ch = (t2 >> 11) & 7;
                const int k = 16 * ch + 8 * (lane >> 5) + el;
                const int hh = ht * 32 + (lane & 31);
                W1p[t2] = f2bf(W1[k * HH + hh]);
            } else {
                const int t3 = t - 26624;
                const int el = t3 & 7, lane = (t3 >> 3) & 63, ht = (t3 >> 9) & 1, ch = t3 >> 10;
                const int k = 16 * ch + 8 * (lane >> 5) + el;
                const int hh = ht * 32 + (lane & 31);
                W2p[t3] = f2bf(W2[k * FF + hh]);
            }
        }
    }
}

// ---------------- Kernel 2: S[b,i,h] = sum_j relu(pair)  (pure MFMA j-loop) ----------------
// One block per (b,i), 4 waves; wave w owns h-tile w, iterates all 8 j-tiles, K=80.
__global__ __launch_bounds__(256) void k_pair(
    const float* __restrict__ e, const float* __restrict__ net,
    const short* __restrict__ xbf, const short* __restrict__ Bpack,
    float* __restrict__ S)
{
    const int row  = blockIdx.x;            // b*256 + i
    const int b    = row >> 8;
    const int tid  = threadIdx.x;
    const int wave = tid >> 6;              // my h-tile
    const int lane = tid & 63;
    const int c    = lane & 31;
    const int half = lane >> 5;

    const bf16x8* __restrict__ bp = (const bf16x8*)Bpack;
    bf16x8 bfrag[NCH];
    #pragma unroll
    for (int ch = 0; ch < NCH; ++ch)
        bfrag[ch] = bp[(ch * 4 + wave) * 64 + lane];

    const float netv = net[(size_t)row * HH + wave * 32 + c];

    const float* __restrict__ eRow = e + (size_t)row * (NN * EE);
    const short* __restrict__ xb   = xbf + (size_t)b * (NN * FF);

    float acc = 0.f;

    #pragma unroll 2
    for (int jt = 0; jt < 8; ++jt) {
        const int j = jt * 32 + c;

        const float4* ap = (const float4*)(eRow + (size_t)j * EE + 8 * half);
        const float4 p0 = ap[0];
        const float4 p1 = ap[1];
        bfu ae;
        ae.u[0] = pkbf(p0.x, p0.y);
        ae.u[1] = pkbf(p0.z, p0.w);
        ae.u[2] = pkbf(p1.x, p1.y);
        ae.u[3] = pkbf(p1.z, p1.w);

        const bf16x8* xp = (const bf16x8*)(xb + (size_t)j * FF + 8 * half);
        const bf16x8 ax0 = xp[0];
        const bf16x8 ax1 = xp[2];
        const bf16x8 ax2 = xp[4];
        const bf16x8 ax3 = xp[6];

        f32x16 d = {netv,netv,netv,netv, netv,netv,netv,netv,
                    netv,netv,netv,netv, netv,netv,netv,netv};
        d = __builtin_amdgcn_mfma_f32_32x32x16_bf16(ae.v, bfrag[0], d, 0, 0, 0);
        d = __builtin_amdgcn_mfma_f32_32x32x16_bf16(ax0,  bfrag[1], d, 0, 0, 0);
        d = __builtin_amdgcn_mfma_f32_32x32x16_bf16(ax1,  bfrag[2], d, 0, 0, 0);
        d = __builtin_amdgcn_mfma_f32_32x32x16_bf16(ax2,  bfrag[3], d, 0, 0, 0);
        d = __builtin_amdgcn_mfma_f32_32x32x16_bf16(ax3,  bfrag[4], d, 0, 0, 0);
        #pragma unroll
        for (int r = 0; r < 16; ++r) acc += fmaxf(d[r], 0.f);
    }

    acc += __shfl_xor(acc, 32);
    if (lane < 32) S[(size_t)row * HH + wave * 32 + c] = acc;
}

// ---------------- Kernel 3: diag + mean + MLP + residual (all MFMA) ----------------
// 64 blocks x 32 rows, 4 waves; wave w owns h-tile w.
__global__ __launch_bounds__(256) void k_mlp(
    const float* __restrict__ x, const float* __restrict__ e,
    const float* __restrict__ S, const float* __restrict__ net,
    const short* __restrict__ xbf, const short* __restrict__ Bpack,
    const short* __restrict__ W1p, const short* __restrict__ W2p,
    const float* __restrict__ b1, const float* __restrict__ b2,
    float* __restrict__ out)
{
    const int row0 = blockIdx.x * 32;
    const int tid  = threadIdx.x;
    const int wave = tid >> 6;
    const int lane = tid & 63;
    const int c    = lane & 31;
    const int half = lane >> 5;

    __shared__ float Dt[32][132];        // diag staging (row stride 528B, 16B-mult)
    __shared__ short neL[32][136];       // ne bf16 (row stride 272B, 16B-mult)
    __shared__ short h1L[32][136];       // h1 bf16

    // ---- diag: same 5-MFMA chain as k_pair (A row = lane&31 -> global row row0+c) ----
    {
        const int gr = row0 + c;
        const int bb = gr >> 8, ii = gr & (NN - 1);
        const float* ed = e + ((size_t)(bb * NN + ii) * NN + ii) * EE + 8 * half;
        const float4 p0 = ((const float4*)ed)[0];
        const float4 p1 = ((const float4*)ed)[1];
        bfu ae;
        ae.u[0] = pkbf(p0.x, p0.y);
        ae.u[1] = pkbf(p0.z, p0.w);
        ae.u[2] = pkbf(p1.x, p1.y);
        ae.u[3] = pkbf(p1.z, p1.w);

        const bf16x8* xp = (const bf16x8*)(xbf + (size_t)gr * FF + 8 * half);
        const bf16x8 ax0 = xp[0];
        const bf16x8 ax1 = xp[2];
        const bf16x8 ax2 = xp[4];
        const bf16x8 ax3 = xp[6];

        const bf16x8* bp = (const bf16x8*)Bpack;
        f32x16 d = {0.f,0.f,0.f,0.f, 0.f,0.f,0.f,0.f, 0.f,0.f,0.f,0.f, 0.f,0.f,0.f,0.f};
        d = __builtin_amdgcn_mfma_f32_32x32x16_bf16(ae.v, bp[(0*4+wave)*64+lane], d, 0, 0, 0);
        d = __builtin_amdgcn_mfma_f32_32x32x16_bf16(ax0,  bp[(1*4+wave)*64+lane], d, 0, 0, 0);
        d = __builtin_amdgcn_mfma_f32_32x32x16_bf16(ax1,  bp[(2*4+wave)*64+lane], d, 0, 0, 0);
        d = __builtin_amdgcn_mfma_f32_32x32x16_bf16(ax2,  bp[(3*4+wave)*64+lane], d, 0, 0, 0);
        d = __builtin_amdgcn_mfma_f32_32x32x16_bf16(ax3,  bp[(4*4+wave)*64+lane], d, 0, 0, 0);
        #pragma unroll
        for (int r = 0; r < 16; ++r) {
            const int rowj = (r & 3) + 8 * (r >> 2) + 4 * half;
            Dt[rowj][wave * 32 + c] = d[r];
        }
    }
    __syncthreads();

    // ---- elementwise: ne = (S - relu(diag + net)) / 256, to bf16 in neL ----
    {
        const int r  = tid >> 3;          // 0..31
        const int h0 = (tid & 7) * 16;    // 0..112
        const size_t base = (size_t)(row0 + r) * HH + h0;
        unsigned uo[8];
        #pragma unroll
        for (int q = 0; q < 4; ++q) {
            const float4 sv = *(const float4*)&S[base + 4 * q];
            const float4 nv = *(const float4*)&net[base + 4 * q];
            const float4 dv = *(const float4*)&Dt[r][h0 + 4 * q];
            const float n0 = (sv.x - fmaxf(dv.x + nv.x, 0.f)) * (1.0f / NN);
            const float n1 = (sv.y - fmaxf(dv.y + nv.y, 0.f)) * (1.0f / NN);
            const float n2 = (sv.z - fmaxf(dv.z + nv.z, 0.f)) * (1.0f / NN);
            const float n3 = (sv.w - fmaxf(dv.w + nv.w, 0.f)) * (1.0f / NN);
            uo[2 * q]     = pkbf(n0, n1);
            uo[2 * q + 1] = pkbf(n2, n3);
        }
        uint4* dst = (uint4*)&neL[r][h0];
        dst[0] = make_uint4(uo[0], uo[1], uo[2], uo[3]);
        dst[1] = make_uint4(uo[4], uo[5], uo[6], uo[7]);
    }
    __syncthreads();

    // ---- h1 = relu(ne @ W1 + b1), K=128 = 8 chunks ----
    {
        const float b1v = b1[wave * 32 + c];
        const bf16x8* wp = (const bf16x8*)W1p;
        f32x16 d = {b1v,b1v,b1v,b1v, b1v,b1v,b1v,b1v, b1v,b1v,b1v,b1v, b1v,b1v,b1v,b1v};
        #pragma unroll
        for (int ch = 0; ch < 8; ++ch) {
            const bf16x8 a = *(const bf16x8*)&neL[c][16 * ch + 8 * half];
            d = __builtin_amdgcn_mfma_f32_32x32x16_bf16(a, wp[(ch * 4 + wave) * 64 + lane], d, 0, 0, 0);
        }
        #pragma unroll
        for (int r = 0; r < 16; ++r) {
            const int rowj = (r & 3) + 8 * (r >> 2) + 4 * half;
            h1L[rowj][wave * 32 + c] = f2bf(fmaxf(d[r], 0.f));
        }
    }
    __syncthreads();

    // ---- out = h1 @ W2 + b2 + x, N=64 -> waves 0,1 ----
    if (wave < 2) {
        const float b2v = b2[wave * 32 + c];
        const bf16x8* wp = (const bf16x8*)W2p;
        f32x16 d = {b2v,b2v,b2v,b2v, b2v,b2v,b2v,b2v, b2v,b2v,b2v,b2v, b2v,b2v,b2v,b2v};
        #pragma unroll
        for (int ch = 0; ch < 8; ++ch) {
            const bf16x8 a = *(const bf16x8*)&h1L[c][16 * ch + 8 * half];
            d = __builtin_amdgcn_mfma_f32_32x32x16_bf16(a, wp[(ch * 2 + wave) * 64 + lane], d, 0, 0, 0);
        }
        #pragma unroll
        for (int r = 0; r < 16; ++r) {
            const int rowj = (r & 3) + 8 * (r >> 2) + 4 * half;
            const size_t idx = (size_t)(row0 + rowj) * FF + wave * 32 + c;
            out[idx] = d[r] + x[idx];
        }
    }
}

extern "C" void kernel_launch(void* const* d_in, const int* in_sizes, int n_in,
                              void* d_out, int out_size, void* d_ws, size_t ws_size,
                              hipStream_t stream) {
    (void)in_sizes; (void)n_in; (void)out_size; (void)ws_size;
    const float* x  = (const float*)d_in[0];
    const float* e  = (const float*)d_in[1];
    const float* Wf = (const float*)d_in[2];
    const float* bf = (const float*)d_in[3];
    const float* Wt = (const float*)d_in[4];
    const float* bt = (const float*)d_in[5];
    const float* We = (const float*)d_in[6];
    const float* be = (const float*)d_in[7];
    const float* W1 = (const float*)d_in[8];
    const float* b1 = (const float*)d_in[9];
    const float* W2 = (const float*)d_in[10];
    const float* b2 = (const float*)d_in[11];
    float* out = (float*)d_out;

    // ws: net 1MB | S 1MB | xbf 256KB | Bpack 20KB | W1p 32KB | W2p 16KB
    char* w = (char*)d_ws;
    float* net   = (float*)w;                 w += (size_t)BB * NN * HH * 4;
    float* Sbuf  = (float*)w;                 w += (size_t)BB * NN * HH * 4;
    short* xbf   = (short*)w;                 w += (size_t)BB * NN * FF * 2;
    short* Bpack = (short*)w;                 w += NCH * 4 * 64 * 8 * 2;
    short* W1p   = (short*)w;                 w += 8 * 4 * 64 * 8 * 2;
    short* W2p   = (short*)w;

    k_prep<<<(BB * NN) / 4, 128, 0, stream>>>(x, Wt, bf, bt, be, We, Wf, W1, W2,
                                              net, xbf, Bpack, W1p, W2p);
    k_pair<<<BB * NN, 256, 0, stream>>>(e, net, xbf, Bpack, Sbuf);
    k_mlp<<<(BB * NN) / 32, 256, 0, stream>>>(x, e, Sbuf, net, xbf, Bpack, W1p, W2p,
                                              b1, b2, out);
}

// Round 9
// 122.440 us; speedup vs baseline: 1.3305x; 1.1310x over previous
//
#include <hip/hip_runtime.h>
#include <hip/hip_bf16.h>

// GraphResBlock: B=8, N=256, F=64(N_IN), H=128(N_HID), E=16(EIN)
// pair[b,i,j,h] = e[b,i,j,:]@We[:,h] + x[b,j,:]@Wf[:,h] + net'[b,i,h]
//   (net' = x@Wt + bf+bt+be)
// S[b,i,h] = sum_j relu(pair)  (incl. j=i)  -> k_pair (MFMA K=80, LDS-staged e, prepacked x)
// ne = (S - relu(diag))/256 ; out = relu(ne@W1+b1)@W2+b2+x  -> k_mlp (MFMA)

#define BB 8
#define NN 256
#define FF 64
#define HH 128
#define EE 16
#define NCH 5   // K chunks for pair: 0 = We(16), 1..4 = Wf(64)

typedef __attribute__((ext_vector_type(8))) short bf16x8;
typedef __attribute__((ext_vector_type(16))) float f32x16;

__device__ __forceinline__ short f2bf(float f) {
    union { float f; unsigned u; } v; v.f = f;
    unsigned r = v.u + 0x7FFFu + ((v.u >> 16) & 1u);   // RNE
    return (short)(r >> 16);
}
__device__ __forceinline__ float bf2f(short s) {
    union { unsigned u; float f; } v; v.u = ((unsigned)(unsigned short)s) << 16;
    return v.f;
}
// packed RNE conversion: dst = {bf16(lo), bf16(hi)}
__device__ __forceinline__ unsigned pkbf(float lo, float hi) {
    unsigned r;
    asm("v_cvt_pk_bf16_f32 %0, %1, %2" : "=v"(r) : "v"(lo), "v"(hi));
    return r;
}
union bfu { bf16x8 v; unsigned u[4]; };

// ---------------- Kernel 1: net' = x@Wt+(bf+bt+be); xbf; xbfp (frag-order); pack B'/W1/W2 ----------------
__global__ __launch_bounds__(128) void k_prep(
    const float* __restrict__ x, const float* __restrict__ Wt,
    const float* __restrict__ bf, const float* __restrict__ bt, const float* __restrict__ be,
    const float* __restrict__ We, const float* __restrict__ Wf,
    const float* __restrict__ W1, const float* __restrict__ W2,
    float* __restrict__ net, short* __restrict__ xbf, short* __restrict__ xbfp,
    short* __restrict__ Bpack, short* __restrict__ W1p, short* __restrict__ W2p)
{
    __shared__ float smx[4 * FF];
    const int tid = threadIdx.x;
    const int row0 = blockIdx.x * 4;

    smx[tid]       = x[(size_t)row0 * FF + tid];
    smx[tid + 128] = x[(size_t)row0 * FF + tid + 128];
    __syncthreads();

    const int h = tid;
    const float bsum = bf[h] + bt[h] + be[h];
    float a0 = bsum, a1 = bsum, a2 = bsum, a3 = bsum;

    #pragma unroll 8
    for (int k = 0; k < FF; ++k) {
        const float wt = Wt[k * HH + h];
        a0 = fmaf(smx[k], wt, a0);
        a1 = fmaf(smx[FF + k], wt, a1);
        a2 = fmaf(smx[2 * FF + k], wt, a2);
        a3 = fmaf(smx[3 * FF + k], wt, a3);
    }
    net[(size_t)(row0 + 0) * HH + h] = a0;
    net[(size_t)(row0 + 1) * HH + h] = a1;
    net[(size_t)(row0 + 2) * HH + h] = a2;
    net[(size_t)(row0 + 3) * HH + h] = a3;

    // bf16 copy of x (row-major, used by k_mlp diag)
    {
        const int r = tid >> 6, f = tid & 63;
        xbf[(size_t)(row0 + r) * FF + f]     = f2bf(smx[r * FF + f]);
        xbf[(size_t)(row0 + r + 2) * FF + f] = f2bf(smx[(r + 2) * FF + f]);
    }

    // x in MFMA fragment order: xbfp[bb][jt][ch][lane][el] (k = 16*ch + 8*half + el)
    {
        const int r    = tid >> 5;        // 0..3 local row
        const int q    = tid & 31;
        const int ch   = q >> 3;          // 0..3
        const int half = (q >> 2) & 1;
        const int el2  = q & 3;
        const int gj   = row0 + r;
        const int bb   = gj >> 8;
        const int jj   = gj & 255;
        const int jt   = jj >> 5;
        const int cc   = jj & 31;
        const float lo = smx[r * FF + ch * 16 + half * 8 + el2 * 2];
        const float hi = smx[r * FF + ch * 16 + half * 8 + el2 * 2 + 1];
        ((unsigned*)xbfp)[((((size_t)bb * 8 + jt) * 4 + ch) * 64 + half * 32 + cc) * 4 + el2]
            = pkbf(lo, hi);
    }

    // ---- pack B'=[We;Wf] (10240), W1 (16384), W2 (8192) into MFMA frag layout ----
    // layout [ch][ht][lane][el]: k = 16*ch_local + 8*(lane>>5) + el, h = ht*32 + (lane&31)
    if (blockIdx.x < 32) {
        for (int t = blockIdx.x * 128 + tid; t < 34816; t += 32 * 128) {
            if (t < 10240) {
                const int el = t & 7, lane = (t >> 3) & 63, ht = (t >> 9) & 3, ch = t >> 11;
                const int kl = 8 * (lane >> 5) + el;
                const int hh = ht * 32 + (lane & 31);
                Bpack[t] = f2bf(ch == 0 ? We[kl * HH + hh] : Wf[(16 * (ch - 1) + kl) * HH + hh]);
            } else if (t < 26624) {
                const int t2 = t - 10240;
                const int el = t2 & 7, lane = (t2 >> 3) & 63, ht = (t2 >> 9) & 3, ch = (t2 >> 11) & 7;
                const int k = 16 * ch + 8 * (lane >> 5) + el;
                const int hh = ht * 32 + (lane & 31);
                W1p[t2] = f2bf(W1[k * HH + hh]);
            } else {
                const int t3 = t - 26624;
                const int el = t3 & 7, lane = (t3 >> 3) & 63, ht = (t3 >> 9) & 1, ch = t3 >> 10;
                const int k = 16 * ch + 8 * (lane >> 5) + el;
                const int hh = ht * 32 + (lane & 31);
                W2p[t3] = f2bf(W2[k * FF + hh]);
            }
        }
    }
}

// ---------------- Kernel 2: S[b,i,h] = sum_j relu(pair)  (coalesced + LDS-staged e) ----------------
// One block per (b,i), 4 waves; wave w owns h-tile w; all waves share the LDS e-tile.
__global__ __launch_bounds__(256) void k_pair(
    const float* __restrict__ e, const float* __restrict__ net,
    const short* __restrict__ xbfp, const short* __restrict__ Bpack,
    float* __restrict__ S)
{
    const int row  = blockIdx.x;            // b*256 + i
    const int b    = row >> 8;
    const int tid  = threadIdx.x;
    const int wave = tid >> 6;              // my h-tile
    const int lane = tid & 63;
    const int c    = lane & 31;
    const int half = lane >> 5;

    // e tile double buffer, fragment-friendly layout [half][c][k8] (1 KB per buf)
    __shared__ __align__(16) char eL[2][1024];

    const bf16x8* __restrict__ bp = (const bf16x8*)Bpack;
    bf16x8 bfrag[NCH];
    #pragma unroll
    for (int ch = 0; ch < NCH; ++ch)
        bfrag[ch] = bp[(ch * 4 + wave) * 64 + lane];

    const float netv = net[(size_t)row * HH + wave * 32 + c];

    const float* __restrict__ eRow = e + (size_t)row * (NN * EE);
    const bf16x8* __restrict__ xq  = (const bf16x8*)(xbfp + (size_t)b * 8 * 4 * 512);

    // staging geometry: thread t holds e elements (row sc, k=2*sk2, 2*sk2+1) of the tile
    const int sc   = tid >> 3;              // 0..31
    const int sk2  = tid & 7;               // k-pair index
    const int edst = ((sk2 >> 2) * 128 + sc * 4 + (sk2 & 3)) * 4;   // byte offset in buf

    // prologue: stage tile 0
    float2 ev = *(const float2*)(eRow + (size_t)tid * 2);
    *(unsigned*)(&eL[0][edst]) = pkbf(ev.x, ev.y);
    __syncthreads();

    float acc0 = 0.f, acc1 = 0.f, acc2 = 0.f, acc3 = 0.f;

    #pragma unroll 2
    for (int jt = 0; jt < 8; ++jt) {
        const int buf = jt & 1;
        // issue next e-tile global load early (hides under MFMA)
        if (jt < 7) ev = *(const float2*)(eRow + (size_t)(jt + 1) * 512 + tid * 2);

        // A fragments: e from LDS, x from prepacked global (coalesced, L2-hit)
        const bf16x8 ae  = *(const bf16x8*)(&eL[buf][half * 512 + c * 16]);
        const bf16x8 ax0 = xq[((size_t)jt * 4 + 0) * 64 + lane];
        const bf16x8 ax1 = xq[((size_t)jt * 4 + 1) * 64 + lane];
        const bf16x8 ax2 = xq[((size_t)jt * 4 + 2) * 64 + lane];
        const bf16x8 ax3 = xq[((size_t)jt * 4 + 3) * 64 + lane];

        f32x16 d = {netv,netv,netv,netv, netv,netv,netv,netv,
                    netv,netv,netv,netv, netv,netv,netv,netv};
        d = __builtin_amdgcn_mfma_f32_32x32x16_bf16(ae,  bfrag[0], d, 0, 0, 0);
        d = __builtin_amdgcn_mfma_f32_32x32x16_bf16(ax0, bfrag[1], d, 0, 0, 0);
        d = __builtin_amdgcn_mfma_f32_32x32x16_bf16(ax1, bfrag[2], d, 0, 0, 0);
        d = __builtin_amdgcn_mfma_f32_32x32x16_bf16(ax2, bfrag[3], d, 0, 0, 0);
        d = __builtin_amdgcn_mfma_f32_32x32x16_bf16(ax3, bfrag[4], d, 0, 0, 0);

        // stage next tile into the other buffer (after compute reads issued)
        if (jt < 7) *(unsigned*)(&eL[buf ^ 1][edst]) = pkbf(ev.x, ev.y);

        #pragma unroll
        for (int r = 0; r < 16; r += 4) {
            acc0 += fmaxf(d[r + 0], 0.f);
            acc1 += fmaxf(d[r + 1], 0.f);
            acc2 += fmaxf(d[r + 2], 0.f);
            acc3 += fmaxf(d[r + 3], 0.f);
        }
        __syncthreads();
    }

    float acc = (acc0 + acc1) + (acc2 + acc3);
    acc += __shfl_xor(acc, 32);
    if (lane < 32) S[(size_t)row * HH + wave * 32 + c] = acc;
}

// ---------------- Kernel 3: diag + mean + MLP + residual (all MFMA) ----------------
// 64 blocks x 32 rows, 4 waves; wave w owns h-tile w.
__global__ __launch_bounds__(256) void k_mlp(
    const float* __restrict__ x, const float* __restrict__ e,
    const float* __restrict__ S, const float* __restrict__ net,
    const short* __restrict__ xbf, const short* __restrict__ Bpack,
    const short* __restrict__ W1p, const short* __restrict__ W2p,
    const float* __restrict__ b1, const float* __restrict__ b2,
    float* __restrict__ out)
{
    const int row0 = blockIdx.x * 32;
    const int tid  = threadIdx.x;
    const int wave = tid >> 6;
    const int lane = tid & 63;
    const int c    = lane & 31;
    const int half = lane >> 5;

    __shared__ float Dt[32][132];        // diag staging
    __shared__ short neL[32][136];       // ne bf16
    __shared__ short h1L[32][136];       // h1 bf16

    // ---- diag: same 5-MFMA chain as k_pair (A row = lane&31 -> global row row0+c) ----
    {
        const int gr = row0 + c;
        const int bb = gr >> 8, ii = gr & (NN - 1);
        const float* ed = e + ((size_t)(bb * NN + ii) * NN + ii) * EE + 8 * half;
        const float4 p0 = ((const float4*)ed)[0];
        const float4 p1 = ((const float4*)ed)[1];
        bfu ae;
        ae.u[0] = pkbf(p0.x, p0.y);
        ae.u[1] = pkbf(p0.z, p0.w);
        ae.u[2] = pkbf(p1.x, p1.y);
        ae.u[3] = pkbf(p1.z, p1.w);

        const bf16x8* xp = (const bf16x8*)(xbf + (size_t)gr * FF + 8 * half);
        const bf16x8 ax0 = xp[0];
        const bf16x8 ax1 = xp[2];
        const bf16x8 ax2 = xp[4];
        const bf16x8 ax3 = xp[6];

        const bf16x8* bp = (const bf16x8*)Bpack;
        f32x16 d = {0.f,0.f,0.f,0.f, 0.f,0.f,0.f,0.f, 0.f,0.f,0.f,0.f, 0.f,0.f,0.f,0.f};
        d = __builtin_amdgcn_mfma_f32_32x32x16_bf16(ae.v, bp[(0*4+wave)*64+lane], d, 0, 0, 0);
        d = __builtin_amdgcn_mfma_f32_32x32x16_bf16(ax0,  bp[(1*4+wave)*64+lane], d, 0, 0, 0);
        d = __builtin_amdgcn_mfma_f32_32x32x16_bf16(ax1,  bp[(2*4+wave)*64+lane], d, 0, 0, 0);
        d = __builtin_amdgcn_mfma_f32_32x32x16_bf16(ax2,  bp[(3*4+wave)*64+lane], d, 0, 0, 0);
        d = __builtin_amdgcn_mfma_f32_32x32x16_bf16(ax3,  bp[(4*4+wave)*64+lane], d, 0, 0, 0);
        #pragma unroll
        for (int r = 0; r < 16; ++r) {
            const int rowj = (r & 3) + 8 * (r >> 2) + 4 * half;
            Dt[rowj][wave * 32 + c] = d[r];
        }
    }
    __syncthreads();

    // ---- elementwise: ne = (S - relu(diag + net)) / 256, to bf16 in neL ----
    {
        const int r  = tid >> 3;          // 0..31
        const int h0 = (tid & 7) * 16;    // 0..112
        const size_t base = (size_t)(row0 + r) * HH + h0;
        unsigned uo[8];
        #pragma unroll
        for (int q = 0; q < 4; ++q) {
            const float4 sv = *(const float4*)&S[base + 4 * q];
            const float4 nv = *(const float4*)&net[base + 4 * q];
            const float4 dv = *(const float4*)&Dt[r][h0 + 4 * q];
            const float n0 = (sv.x - fmaxf(dv.x + nv.x, 0.f)) * (1.0f / NN);
            const float n1 = (sv.y - fmaxf(dv.y + nv.y, 0.f)) * (1.0f / NN);
            const float n2 = (sv.z - fmaxf(dv.z + nv.z, 0.f)) * (1.0f / NN);
            const float n3 = (sv.w - fmaxf(dv.w + nv.w, 0.f)) * (1.0f / NN);
            uo[2 * q]     = pkbf(n0, n1);
            uo[2 * q + 1] = pkbf(n2, n3);
        }
        uint4* dst = (uint4*)&neL[r][h0];
        dst[0] = make_uint4(uo[0], uo[1], uo[2], uo[3]);
        dst[1] = make_uint4(uo[4], uo[5], uo[6], uo[7]);
    }
    __syncthreads();

    // ---- h1 = relu(ne @ W1 + b1), K=128 = 8 chunks ----
    {
        const float b1v = b1[wave * 32 + c];
        const bf16x8* wp = (const bf16x8*)W1p;
        f32x16 d = {b1v,b1v,b1v,b1v, b1v,b1v,b1v,b1v, b1v,b1v,b1v,b1v, b1v,b1v,b1v,b1v};
        #pragma unroll
        for (int ch = 0; ch < 8; ++ch) {
            const bf16x8 a = *(const bf16x8*)&neL[c][16 * ch + 8 * half];
            d = __builtin_amdgcn_mfma_f32_32x32x16_bf16(a, wp[(ch * 4 + wave) * 64 + lane], d, 0, 0, 0);
        }
        #pragma unroll
        for (int r = 0; r < 16; ++r) {
            const int rowj = (r & 3) + 8 * (r >> 2) + 4 * half;
            h1L[rowj][wave * 32 + c] = f2bf(fmaxf(d[r], 0.f));
        }
    }
    __syncthreads();

    // ---- out = h1 @ W2 + b2 + x, N=64 -> waves 0,1 ----
    if (wave < 2) {
        const float b2v = b2[wave * 32 + c];
        const bf16x8* wp = (const bf16x8*)W2p;
        f32x16 d = {b2v,b2v,b2v,b2v, b2v,b2v,b2v,b2v, b2v,b2v,b2v,b2v, b2v,b2v,b2v,b2v};
        #pragma unroll
        for (int ch = 0; ch < 8; ++ch) {
            const bf16x8 a = *(const bf16x8*)&h1L[c][16 * ch + 8 * half];
            d = __builtin_amdgcn_mfma_f32_32x32x16_bf16(a, wp[(ch * 2 + wave) * 64 + lane], d, 0, 0, 0);
        }
        #pragma unroll
        for (int r = 0; r < 16; ++r) {
            const int rowj = (r & 3) + 8 * (r >> 2) + 4 * half;
            const size_t idx = (size_t)(row0 + rowj) * FF + wave * 32 + c;
            out[idx] = d[r] + x[idx];
        }
    }
}

extern "C" void kernel_launch(void* const* d_in, const int* in_sizes, int n_in,
                              void* d_out, int out_size, void* d_ws, size_t ws_size,
                              hipStream_t stream) {
    (void)in_sizes; (void)n_in; (void)out_size; (void)ws_size;
    const float* x  = (const float*)d_in[0];
    const float* e  = (const float*)d_in[1];
    const float* Wf = (const float*)d_in[2];
    const float* bf = (const float*)d_in[3];
    const float* Wt = (const float*)d_in[4];
    const float* bt = (const float*)d_in[5];
    const float* We = (const float*)d_in[6];
    const float* be = (const float*)d_in[7];
    const float* W1 = (const float*)d_in[8];
    const float* b1 = (const float*)d_in[9];
    const float* W2 = (const float*)d_in[10];
    const float* b2 = (const float*)d_in[11];
    float* out = (float*)d_out;

    // ws: net 1MB | S 1MB | xbf 256KB | xbfp 256KB | Bpack 20KB | W1p 32KB | W2p 16KB
    char* w = (char*)d_ws;
    float* net   = (float*)w;                 w += (size_t)BB * NN * HH * 4;
    float* Sbuf  = (float*)w;                 w += (size_t)BB * NN * HH * 4;
    short* xbf   = (short*)w;                 w += (size_t)BB * NN * FF * 2;
    short* xbfp  = (short*)w;                 w += (size_t)BB * NN * FF * 2;
    short* Bpack = (short*)w;                 w += NCH * 4 * 64 * 8 * 2;
    short* W1p   = (short*)w;                 w += 8 * 4 * 64 * 8 * 2;
    short* W2p   = (short*)w;

    k_prep<<<(BB * NN) / 4, 128, 0, stream>>>(x, Wt, bf, bt, be, We, Wf, W1, W2,
                                              net, xbf, xbfp, Bpack, W1p, W2p);
    k_pair<<<BB * NN, 256, 0, stream>>>(e, net, xbfp, Bpack, Sbuf);
    k_mlp<<<(BB * NN) / 32, 256, 0, stream>>>(x, e, Sbuf, net, xbf, Bpack, W1p, W2p,
                                              b1, b2, out);
}

// Round 10
// 118.992 us; speedup vs baseline: 1.3691x; 1.0290x over previous
//
#include <hip/hip_runtime.h>
#include <hip/hip_bf16.h>

// GraphResBlock: B=8, N=256, F=64(N_IN), H=128(N_HID), E=16(EIN)
// pair[b,i,j,h] = e[b,i,j,:]@We[:,h] + x[b,j,:]@Wf[:,h] + net'[b,i,h]
//   (net' = x@Wt + bf+bt+be)
// S[b,i,h] = sum_j relu(pair)  (incl. j=i)  -> k_pair (MFMA K=80, whole-row LDS e, prepacked x)
// ne = (S - relu(diag))/256 ; out = relu(ne@W1+b1)@W2+b2+x  -> k_mlp (MFMA)

#define BB 8
#define NN 256
#define FF 64
#define HH 128
#define EE 16
#define NCH 5   // K chunks for pair: 0 = We(16), 1..4 = Wf(64)

typedef __attribute__((ext_vector_type(8))) short bf16x8;
typedef __attribute__((ext_vector_type(16))) float f32x16;

__device__ __forceinline__ short f2bf(float f) {
    union { float f; unsigned u; } v; v.f = f;
    unsigned r = v.u + 0x7FFFu + ((v.u >> 16) & 1u);   // RNE
    return (short)(r >> 16);
}
__device__ __forceinline__ float bf2f(short s) {
    union { unsigned u; float f; } v; v.u = ((unsigned)(unsigned short)s) << 16;
    return v.f;
}
// packed RNE conversion: dst = {bf16(lo), bf16(hi)}
__device__ __forceinline__ unsigned pkbf(float lo, float hi) {
    unsigned r;
    asm("v_cvt_pk_bf16_f32 %0, %1, %2" : "=v"(r) : "v"(lo), "v"(hi));
    return r;
}
union bfu { bf16x8 v; unsigned u[4]; };

// ---------------- Kernel 1: net' = x@Wt+(bf+bt+be); xbf; xbfp (frag-order); pack B'/W1/W2 ----------------
__global__ __launch_bounds__(128) void k_prep(
    const float* __restrict__ x, const float* __restrict__ Wt,
    const float* __restrict__ bf, const float* __restrict__ bt, const float* __restrict__ be,
    const float* __restrict__ We, const float* __restrict__ Wf,
    const float* __restrict__ W1, const float* __restrict__ W2,
    float* __restrict__ net, short* __restrict__ xbf, short* __restrict__ xbfp,
    short* __restrict__ Bpack, short* __restrict__ W1p, short* __restrict__ W2p)
{
    __shared__ float smx[4 * FF];
    const int tid = threadIdx.x;
    const int row0 = blockIdx.x * 4;

    smx[tid]       = x[(size_t)row0 * FF + tid];
    smx[tid + 128] = x[(size_t)row0 * FF + tid + 128];
    __syncthreads();

    const int h = tid;
    const float bsum = bf[h] + bt[h] + be[h];
    float a0 = bsum, a1 = bsum, a2 = bsum, a3 = bsum;

    #pragma unroll 8
    for (int k = 0; k < FF; ++k) {
        const float wt = Wt[k * HH + h];
        a0 = fmaf(smx[k], wt, a0);
        a1 = fmaf(smx[FF + k], wt, a1);
        a2 = fmaf(smx[2 * FF + k], wt, a2);
        a3 = fmaf(smx[3 * FF + k], wt, a3);
    }
    net[(size_t)(row0 + 0) * HH + h] = a0;
    net[(size_t)(row0 + 1) * HH + h] = a1;
    net[(size_t)(row0 + 2) * HH + h] = a2;
    net[(size_t)(row0 + 3) * HH + h] = a3;

    // bf16 copy of x (row-major, used by k_mlp diag)
    {
        const int r = tid >> 6, f = tid & 63;
        xbf[(size_t)(row0 + r) * FF + f]     = f2bf(smx[r * FF + f]);
        xbf[(size_t)(row0 + r + 2) * FF + f] = f2bf(smx[(r + 2) * FF + f]);
    }

    // x in MFMA fragment order: xbfp[bb][jt][ch][lane][el] (k = 16*ch + 8*half + el)
    {
        const int r    = tid >> 5;        // 0..3 local row
        const int q    = tid & 31;
        const int ch   = q >> 3;          // 0..3
        const int half = (q >> 2) & 1;
        const int el2  = q & 3;
        const int gj   = row0 + r;
        const int bb   = gj >> 8;
        const int jj   = gj & 255;
        const int jt   = jj >> 5;
        const int cc   = jj & 31;
        const float lo = smx[r * FF + ch * 16 + half * 8 + el2 * 2];
        const float hi = smx[r * FF + ch * 16 + half * 8 + el2 * 2 + 1];
        ((unsigned*)xbfp)[((((size_t)bb * 8 + jt) * 4 + ch) * 64 + half * 32 + cc) * 4 + el2]
            = pkbf(lo, hi);
    }

    // ---- pack B'=[We;Wf] (10240), W1 (16384), W2 (8192) into MFMA frag layout ----
    // layout [ch][ht][lane][el]: k = 16*ch_local + 8*(lane>>5) + el, h = ht*32 + (lane&31)
    if (blockIdx.x < 32) {
        for (int t = blockIdx.x * 128 + tid; t < 34816; t += 32 * 128) {
            if (t < 10240) {
                const int el = t & 7, lane = (t >> 3) & 63, ht = (t >> 9) & 3, ch = t >> 11;
                const int kl = 8 * (lane >> 5) + el;
                const int hh = ht * 32 + (lane & 31);
                Bpack[t] = f2bf(ch == 0 ? We[kl * HH + hh] : Wf[(16 * (ch - 1) + kl) * HH + hh]);
            } else if (t < 26624) {
                const int t2 = t - 10240;
                const int el = t2 & 7, lane = (t2 >> 3) & 63, ht = (t2 >> 9) & 3, ch = (t2 >> 11) & 7;
                const int k = 16 * ch + 8 * (lane >> 5) + el;
                const int hh = ht * 32 + (lane & 31);
                W1p[t2] = f2bf(W1[k * HH + hh]);
            } else {
                const int t3 = t - 26624;
                const int el = t3 & 7, lane = (t3 >> 3) & 63, ht = (t3 >> 9) & 1, ch = t3 >> 10;
                const int k = 16 * ch + 8 * (lane >> 5) + el;
                const int hh = ht * 32 + (lane & 31);
                W2p[t3] = f2bf(W2[k * FF + hh]);
            }
        }
    }
}

// ---------------- Kernel 2: S[b,i,h] = sum_j relu(pair)  (whole-row LDS e, 1 barrier) ----------------
// One block per (b,i), 4 waves; wave w owns h-tile w; j-loop is barrier-free.
__global__ __launch_bounds__(256) void k_pair(
    const float* __restrict__ e, const float* __restrict__ net,
    const short* __restrict__ xbfp, const short* __restrict__ Bpack,
    float* __restrict__ S)
{
    const int row  = blockIdx.x;            // b*256 + i
    const int b    = row >> 8;
    const int tid  = threadIdx.x;
    const int wave = tid >> 6;              // my h-tile
    const int lane = tid & 63;
    const int c    = lane & 31;
    const int half = lane >> 5;

    // whole e-row as bf16, tile-major: [jt][half][c][k8] = 8 KB
    __shared__ __align__(16) char eL[8 * 1024];

    const bf16x8* __restrict__ bp = (const bf16x8*)Bpack;
    bf16x8 bfrag[NCH];
    #pragma unroll
    for (int ch = 0; ch < NCH; ++ch)
        bfrag[ch] = bp[(ch * 4 + wave) * 64 + lane];

    const float netv = net[(size_t)row * HH + wave * 32 + c];

    const float* __restrict__ eRow = e + (size_t)row * (NN * EE);
    const bf16x8* __restrict__ xq  = (const bf16x8*)(xbfp + (size_t)b * 8 * 4 * 512);

    // staging geometry: thread t holds e elements (row sc, k=2*sk2, 2*sk2+1) of each tile
    const int sc   = tid >> 3;              // 0..31
    const int sk2  = tid & 7;               // k-pair index
    const int edst = ((sk2 >> 2) * 128 + sc * 4 + (sk2 & 3)) * 4;   // byte offset within tile

    // stage all 8 tiles (independent loads -> deep pipeline, one barrier total)
    #pragma unroll
    for (int jt = 0; jt < 8; ++jt) {
        const float2 ev = *(const float2*)(eRow + (size_t)jt * 512 + tid * 2);
        *(unsigned*)(&eL[jt * 1024 + edst]) = pkbf(ev.x, ev.y);
    }
    __syncthreads();

    float acc0 = 0.f, acc1 = 0.f, acc2 = 0.f, acc3 = 0.f;

    #pragma unroll
    for (int jt = 0; jt < 8; ++jt) {
        // A fragments: e from LDS, x from prepacked global (coalesced, L2-hit)
        const bf16x8 ae  = *(const bf16x8*)(&eL[jt * 1024 + half * 512 + c * 16]);
        const bf16x8 ax0 = xq[((size_t)jt * 4 + 0) * 64 + lane];
        const bf16x8 ax1 = xq[((size_t)jt * 4 + 1) * 64 + lane];
        const bf16x8 ax2 = xq[((size_t)jt * 4 + 2) * 64 + lane];
        const bf16x8 ax3 = xq[((size_t)jt * 4 + 3) * 64 + lane];

        f32x16 d = {netv,netv,netv,netv, netv,netv,netv,netv,
                    netv,netv,netv,netv, netv,netv,netv,netv};
        d = __builtin_amdgcn_mfma_f32_32x32x16_bf16(ae,  bfrag[0], d, 0, 0, 0);
        d = __builtin_amdgcn_mfma_f32_32x32x16_bf16(ax0, bfrag[1], d, 0, 0, 0);
        d = __builtin_amdgcn_mfma_f32_32x32x16_bf16(ax1, bfrag[2], d, 0, 0, 0);
        d = __builtin_amdgcn_mfma_f32_32x32x16_bf16(ax2, bfrag[3], d, 0, 0, 0);
        d = __builtin_amdgcn_mfma_f32_32x32x16_bf16(ax3, bfrag[4], d, 0, 0, 0);

        #pragma unroll
        for (int r = 0; r < 16; r += 4) {
            acc0 += fmaxf(d[r + 0], 0.f);
            acc1 += fmaxf(d[r + 1], 0.f);
            acc2 += fmaxf(d[r + 2], 0.f);
            acc3 += fmaxf(d[r + 3], 0.f);
        }
    }

    float acc = (acc0 + acc1) + (acc2 + acc3);
    acc += __shfl_xor(acc, 32);
    if (lane < 32) S[(size_t)row * HH + wave * 32 + c] = acc;
}

// ---------------- Kernel 3: diag + mean + MLP + residual (all MFMA) ----------------
// 64 blocks x 32 rows, 4 waves; wave w owns h-tile w.
__global__ __launch_bounds__(256) void k_mlp(
    const float* __restrict__ x, const float* __restrict__ e,
    const float* __restrict__ S, const float* __restrict__ net,
    const short* __restrict__ xbf, const short* __restrict__ Bpack,
    const short* __restrict__ W1p, const short* __restrict__ W2p,
    const float* __restrict__ b1, const float* __restrict__ b2,
    float* __restrict__ out)
{
    const int row0 = blockIdx.x * 32;
    const int tid  = threadIdx.x;
    const int wave = tid >> 6;
    const int lane = tid & 63;
    const int c    = lane & 31;
    const int half = lane >> 5;

    __shared__ float Dt[32][132];        // diag staging
    __shared__ short neL[32][136];       // ne bf16
    __shared__ short h1L[32][136];       // h1 bf16

    // ---- diag: same 5-MFMA chain as k_pair (A row = lane&31 -> global row row0+c) ----
    {
        const int gr = row0 + c;
        const int bb = gr >> 8, ii = gr & (NN - 1);
        const float* ed = e + ((size_t)(bb * NN + ii) * NN + ii) * EE + 8 * half;
        const float4 p0 = ((const float4*)ed)[0];
        const float4 p1 = ((const float4*)ed)[1];
        bfu ae;
        ae.u[0] = pkbf(p0.x, p0.y);
        ae.u[1] = pkbf(p0.z, p0.w);
        ae.u[2] = pkbf(p1.x, p1.y);
        ae.u[3] = pkbf(p1.z, p1.w);

        const bf16x8* xp = (const bf16x8*)(xbf + (size_t)gr * FF + 8 * half);
        const bf16x8 ax0 = xp[0];
        const bf16x8 ax1 = xp[2];
        const bf16x8 ax2 = xp[4];
        const bf16x8 ax3 = xp[6];

        const bf16x8* bp = (const bf16x8*)Bpack;
        f32x16 d = {0.f,0.f,0.f,0.f, 0.f,0.f,0.f,0.f, 0.f,0.f,0.f,0.f, 0.f,0.f,0.f,0.f};
        d = __builtin_amdgcn_mfma_f32_32x32x16_bf16(ae.v, bp[(0*4+wave)*64+lane], d, 0, 0, 0);
        d = __builtin_amdgcn_mfma_f32_32x32x16_bf16(ax0,  bp[(1*4+wave)*64+lane], d, 0, 0, 0);
        d = __builtin_amdgcn_mfma_f32_32x32x16_bf16(ax1,  bp[(2*4+wave)*64+lane], d, 0, 0, 0);
        d = __builtin_amdgcn_mfma_f32_32x32x16_bf16(ax2,  bp[(3*4+wave)*64+lane], d, 0, 0, 0);
        d = __builtin_amdgcn_mfma_f32_32x32x16_bf16(ax3,  bp[(4*4+wave)*64+lane], d, 0, 0, 0);
        #pragma unroll
        for (int r = 0; r < 16; ++r) {
            const int rowj = (r & 3) + 8 * (r >> 2) + 4 * half;
            Dt[rowj][wave * 32 + c] = d[r];
        }
    }
    __syncthreads();

    // ---- elementwise: ne = (S - relu(diag + net)) / 256, to bf16 in neL ----
    {
        const int r  = tid >> 3;          // 0..31
        const int h0 = (tid & 7) * 16;    // 0..112
        const size_t base = (size_t)(row0 + r) * HH + h0;
        unsigned uo[8];
        #pragma unroll
        for (int q = 0; q < 4; ++q) {
            const float4 sv = *(const float4*)&S[base + 4 * q];
            const float4 nv = *(const float4*)&net[base + 4 * q];
            const float4 dv = *(const float4*)&Dt[r][h0 + 4 * q];
            const float n0 = (sv.x - fmaxf(dv.x + nv.x, 0.f)) * (1.0f / NN);
            const float n1 = (sv.y - fmaxf(dv.y + nv.y, 0.f)) * (1.0f / NN);
            const float n2 = (sv.z - fmaxf(dv.z + nv.z, 0.f)) * (1.0f / NN);
            const float n3 = (sv.w - fmaxf(dv.w + nv.w, 0.f)) * (1.0f / NN);
            uo[2 * q]     = pkbf(n0, n1);
            uo[2 * q + 1] = pkbf(n2, n3);
        }
        uint4* dst = (uint4*)&neL[r][h0];
        dst[0] = make_uint4(uo[0], uo[1], uo[2], uo[3]);
        dst[1] = make_uint4(uo[4], uo[5], uo[6], uo[7]);
    }
    __syncthreads();

    // ---- h1 = relu(ne @ W1 + b1), K=128 = 8 chunks ----
    {
        const float b1v = b1[wave * 32 + c];
        const bf16x8* wp = (const bf16x8*)W1p;
        f32x16 d = {b1v,b1v,b1v,b1v, b1v,b1v,b1v,b1v, b1v,b1v,b1v,b1v, b1v,b1v,b1v,b1v};
        #pragma unroll
        for (int ch = 0; ch < 8; ++ch) {
            const bf16x8 a = *(const bf16x8*)&neL[c][16 * ch + 8 * half];
            d = __builtin_amdgcn_mfma_f32_32x32x16_bf16(a, wp[(ch * 4 + wave) * 64 + lane], d, 0, 0, 0);
        }
        #pragma unroll
        for (int r = 0; r < 16; ++r) {
            const int rowj = (r & 3) + 8 * (r >> 2) + 4 * half;
            h1L[rowj][wave * 32 + c] = f2bf(fmaxf(d[r], 0.f));
        }
    }
    __syncthreads();

    // ---- out = h1 @ W2 + b2 + x, N=64 -> waves 0,1 ----
    if (wave < 2) {
        const float b2v = b2[wave * 32 + c];
        const bf16x8* wp = (const bf16x8*)W2p;
        f32x16 d = {b2v,b2v,b2v,b2v, b2v,b2v,b2v,b2v, b2v,b2v,b2v,b2v, b2v,b2v,b2v,b2v};
        #pragma unroll
        for (int ch = 0; ch < 8; ++ch) {
            const bf16x8 a = *(const bf16x8*)&h1L[c][16 * ch + 8 * half];
            d = __builtin_amdgcn_mfma_f32_32x32x16_bf16(a, wp[(ch * 2 + wave) * 64 + lane], d, 0, 0, 0);
        }
        #pragma unroll
        for (int r = 0; r < 16; ++r) {
            const int rowj = (r & 3) + 8 * (r >> 2) + 4 * half;
            const size_t idx = (size_t)(row0 + rowj) * FF + wave * 32 + c;
            out[idx] = d[r] + x[idx];
        }
    }
}

extern "C" void kernel_launch(void* const* d_in, const int* in_sizes, int n_in,
                              void* d_out, int out_size, void* d_ws, size_t ws_size,
                              hipStream_t stream) {
    (void)in_sizes; (void)n_in; (void)out_size; (void)ws_size;
    const float* x  = (const float*)d_in[0];
    const float* e  = (const float*)d_in[1];
    const float* Wf = (const float*)d_in[2];
    const float* bf = (const float*)d_in[3];
    const float* Wt = (const float*)d_in[4];
    const float* bt = (const float*)d_in[5];
    const float* We = (const float*)d_in[6];
    const float* be = (const float*)d_in[7];
    const float* W1 = (const float*)d_in[8];
    const float* b1 = (const float*)d_in[9];
    const float* W2 = (const float*)d_in[10];
    const float* b2 = (const float*)d_in[11];
    float* out = (float*)d_out;

    // ws: net 1MB | S 1MB | xbf 256KB | xbfp 256KB | Bpack 20KB | W1p 32KB | W2p 16KB
    char* w = (char*)d_ws;
    float* net   = (float*)w;                 w += (size_t)BB * NN * HH * 4;
    float* Sbuf  = (float*)w;                 w += (size_t)BB * NN * HH * 4;
    short* xbf   = (short*)w;                 w += (size_t)BB * NN * FF * 2;
    short* xbfp  = (short*)w;                 w += (size_t)BB * NN * FF * 2;
    short* Bpack = (short*)w;                 w += NCH * 4 * 64 * 8 * 2;
    short* W1p   = (short*)w;                 w += 8 * 4 * 64 * 8 * 2;
    short* W2p   = (short*)w;

    k_prep<<<(BB * NN) / 4, 128, 0, stream>>>(x, Wt, bf, bt, be, We, Wf, W1, W2,
                                              net, xbf, xbfp, Bpack, W1p, W2p);
    k_pair<<<BB * NN, 256, 0, stream>>>(e, net, xbfp, Bpack, Sbuf);
    k_mlp<<<(BB * NN) / 32, 256, 0, stream>>>(x, e, Sbuf, net, xbf, Bpack, W1p, W2p,
                                              b1, b2, out);
}